// Round 13
// baseline (142.772 us; speedup 1.0000x reference)
//
#include <hip/hip_runtime.h>
#include <hip/hip_bf16.h>
#include <math.h>

#define TT 3
#define HH 96
#define WWD 96
#define CCH 128
#define NROWS (TT*HH*WWD)   // 27648

typedef __attribute__((ext_vector_type(8))) short short8;
typedef __attribute__((ext_vector_type(4))) short short4v;
typedef __attribute__((ext_vector_type(4))) float float4v;

__device__ __forceinline__ float bfu(unsigned short u){ union{unsigned u;float f;}c; c.u=((unsigned)u)<<16; return c.f; }
__device__ __forceinline__ unsigned short f2bf(float f){ __hip_bfloat16 h=__float2bfloat16(f); return *(unsigned short*)&h; }

// ---- 16x16x16 bf16 MFMA (K = d_head = 16) ----
#if defined(__has_builtin)
#if __has_builtin(__builtin_amdgcn_mfma_f32_16x16x16bf16_1k)
#define MFMA16(A,B,C) __builtin_amdgcn_mfma_f32_16x16x16bf16_1k(A,B,C,0,0,0)
#endif
#endif
#ifndef MFMA16
static __device__ __forceinline__ float4v mfma16_asm(short4v a, short4v b, float4v c){
    float4v d;
    asm("v_mfma_f32_16x16x16_bf16 %0, %1, %2, %3" : "=v"(d) : "v"(a), "v"(b), "v"(c));
    return d;
}
#define MFMA16(A,B,C) mfma16_asm(A,B,C)
#endif

// Q pre-scale: 1/sqrt(16) * log2(e)  -> scores live in base-2 domain, exp() becomes native v_exp_f32
#define QSCL 0.36067376022224085f

// ---------------- Kernel 0: weight prep, LDS-tile transpose (coalesced both sides) ----------------
__launch_bounds__(256)
__global__ void prep_kernel(const float* __restrict__ Wq, const float* __restrict__ Wk,
                            const float* __restrict__ Wv, const float* __restrict__ Wo,
                            unsigned short* __restrict__ Wt, unsigned short* __restrict__ Wo1,
                            unsigned short* __restrict__ Wo2) {
    __shared__ float ts[32][33];
    const int m = blockIdx.x >> 4, tile = blockIdx.x & 15;
    const int k0 = (tile >> 2) * 32, n0 = (tile & 3) * 32;
    const float* src = (m == 0) ? Wq : (m == 1) ? Wk : (m == 2) ? Wv : Wo;
    const int tid = threadIdx.x;
    const int c = tid & 31, r8 = tid >> 5;
#pragma unroll
    for (int rr = 0; rr < 4; ++rr) {
        int r = r8 * 4 + rr;
        ts[r][c] = src[(size_t)(k0 + r) * 128 + n0 + c];
    }
    __syncthreads();
#pragma unroll
    for (int rr = 0; rr < 4; ++rr) {
        int r = r8 * 4 + rr;
        float v = ts[c][r];
        if (m < 3) {
            Wt[(size_t)(m * 128 + n0 + r) * 128 + k0 + c] = f2bf(v);
        } else {
            unsigned short w1 = f2bf(v);
            Wo1[(size_t)(n0 + r) * 128 + k0 + c] = w1;
            Wo2[(size_t)(n0 + r) * 128 + k0 + c] = f2bf(v - bfu(w1));
        }
    }
}

// ---------------- Kernel 1: QKV projection, M-tile 64, mt==matrix mapping, LDS coalesced epilogue ----
__launch_bounds__(512)
__global__ void qkv_kernel(const float* __restrict__ x,
                           const unsigned short* __restrict__ Wt,
                           const float* __restrict__ temp_emb,
                           const float* __restrict__ sp_emb,
                           unsigned short* __restrict__ Qb,
                           unsigned short* __restrict__ Kb,
                           unsigned short* __restrict__ Vb) {
    // [0,17408) xs bf16 [64][136]  |  epilogue alias: OF f32 [64][132] = 33792 B
    __shared__ __align__(16) char smem[33792];
    unsigned short* xs = (unsigned short*)smem;
    float* OF          = (float*)smem;

    const int tid = threadIdx.x;
    const int q0 = blockIdx.x * 64;
    const int t = q0 / (HH * WWD);               // uniform per block

    for (int e = tid; e < 2048; e += 512) {
        int row = e >> 5, col = (e & 31) * 4;
        float4 v = *(const float4*)(x + (size_t)(q0 + row) * CCH + col);
        ushort4 u; u.x = f2bf(v.x); u.y = f2bf(v.y); u.z = f2bf(v.z); u.w = f2bf(v.w);
        *(ushort4*)&xs[row * 136 + col] = u;
    }
    __syncthreads();

    const int w = tid >> 6, lane = tid & 63, quad = lane >> 4, l16 = lane & 15;

    float4v acc[3][4];
#pragma unroll
    for (int m = 0; m < 3; ++m)
#pragma unroll
        for (int nt = 0; nt < 4; ++nt) acc[m][nt] = (float4v){0,0,0,0};

#pragma unroll
    for (int ks = 0; ks < 4; ++ks) {
        short8 b[4];
#pragma unroll
        for (int nt = 0; nt < 4; ++nt)
            b[nt] = *(const short8*)&xs[(nt * 16 + l16) * 136 + ks * 32 + quad * 8];
#pragma unroll
        for (int m = 0; m < 3; ++m) {
            short8 a = *(const short8*)(Wt + (size_t)(m * 128 + w * 16 + l16) * CCH + ks * 32 + quad * 8);
#pragma unroll
            for (int nt = 0; nt < 4; ++nt)
                acc[m][nt] = __builtin_amdgcn_mfma_f32_16x16x32_bf16(a, b[nt], acc[m][nt], 0, 0, 0);
        }
    }

    unsigned short* dst[3] = {Qb, Kb, Vb};
#pragma unroll
    for (int m = 0; m < 3; ++m) {
        __syncthreads();
#pragma unroll
        for (int nt = 0; nt < 4; ++nt) {
            float4v a = acc[m][nt];
            float4 o; o.x = a[0]; o.y = a[1]; o.z = a[2]; o.w = a[3];
            *(float4*)&OF[(nt * 16 + l16) * 132 + w * 16 + quad * 4] = o;
        }
        __syncthreads();
        for (int e = tid; e < 2048; e += 512) {
            int row = e >> 5, c4 = (e & 31);
            int ch = c4 * 4;
            float4 v = *(const float4*)&OF[row * 132 + ch];
            int q = q0 + row;
            ushort4 u;
            if (m == 0) {
                int rem = q - t * (HH * WWD);
                int yy = rem / WWD, xx = rem - (rem / WWD) * WWD;
                int qidx = (yy - min(max(yy, 2), 93) + 2) * 5 + (xx - min(max(xx, 2), 93) + 2);
                float4 te = *(const float4*)(temp_emb + t * CCH + ch);
                float4 se = *(const float4*)(sp_emb + qidx * CCH + ch);
                u.x = f2bf((v.x + te.x + se.x) * QSCL);
                u.y = f2bf((v.y + te.y + se.y) * QSCL);
                u.z = f2bf((v.z + te.z + se.z) * QSCL);
                u.w = f2bf((v.w + te.w + se.w) * QSCL);
            } else if (m == 1) {
                float4 te = *(const float4*)(temp_emb + t * CCH + ch);
                u.x = f2bf(v.x + te.x); u.y = f2bf(v.y + te.y);
                u.z = f2bf(v.z + te.z); u.w = f2bf(v.w + te.w);
            } else {
                u.x = f2bf(v.x); u.y = f2bf(v.y); u.z = f2bf(v.z); u.w = f2bf(v.w);
            }
            *(ushort4*)(dst[m] + (size_t)q * CCH + ch) = u;
        }
    }
}

// ---------------- Kernel 2: MFMA flash attention, ALL tiles pre-staged, barrier-free t-loop ----------------
// Block = 4x4 spatial patch. 512 thr = 8 waves, wave = head. exp2 score domain, XCD swizzle.
// R13: ALL 3 K/V tiles staged in one burst (12.75 uint4/thread, one vmcnt drain, ONE barrier),
// then the fully-unrolled 3-t compute runs with ZERO barriers. LDS 145.2 KB -> 1 block/CU;
// measured occupancy at 2 blocks/CU was only ~7.7 waves/CU anyway, so the lost slot is cheap.
// __launch_bounds__(512,2): with LDS pinning 1 block/CU, any VGPR<=256 keeps 2 waves/SIMD,
// so allocator has spill-free room for the staging burst (avoids R10's pin-at-64-and-spill).
#define PX 4
#define WIN 8
#define KTS 8704     // ushorts per K tile (64*136)
#define VTS 8704     // ushorts per V^T tile (128*68)

__launch_bounds__(512, 2)
__global__ void attn_kernel(const unsigned short* __restrict__ Qb,
                            const unsigned short* __restrict__ Kb,
                            const unsigned short* __restrict__ Vb,
                            const float* __restrict__ sp_emb,
                            const unsigned short* __restrict__ Wo1,
                            const unsigned short* __restrict__ Wo2,
                            float* __restrict__ out) {
    // [0,52224)        K tiles [3][64][136] ushort   | epilogue: Os bf16 [48][136] (13056 B)
    // [52224,104448)   V^T     [3][128][68] ushort   | epilogue: OF f32 [48][132] (25344 B)
    // [104448,145248)  bias f32 [8][3][25][17]
    __shared__ __align__(16) char smem[145248];
    unsigned short* Ks = (unsigned short*)smem;
    unsigned short* Vt = (unsigned short*)(smem + 52224);
    float* biasL       = (float*)(smem + 104448);
    unsigned short* Os = (unsigned short*)smem;
    float* OF          = (float*)(smem + 52224);

    const int tid = threadIdx.x;
    const int lane = tid & 63;
    const int w = tid >> 6;                      // head
    const int quad = lane >> 4, l16 = lane & 15;
    const int h16 = w * 16;

    // XCD-aware bijective swizzle: 576 blocks, 8 XCDs, 72 contiguous patches per XCD
    const int wg = (blockIdx.x & 7) * (576 / 8) + (blockIdx.x >> 3);
    const int bx = wg % (WWD / PX);
    const int by = wg / (WWD / PX);
    const int x0 = bx * PX, y0 = by * PX;
    const int xlo = min(max(x0 - 2, 0), WWD - WIN);
    const int ylo = min(max(y0 - 2, 0), HH - WIN);

    const int qdy = l16 >> 2, qdx = l16 & 3;
    const int yy = y0 + qdy, xx = x0 + qdx;
    const int yc = min(max(yy, 2), HH - 3), xc = min(max(xx, 2), WWD - 3);

    // ---- stage ALL 3 K tiles (coalesced uint4) — one burst, max MLP
#pragma unroll
    for (int i = 0; i < 6; ++i) {
        int e = i * 512 + tid;
        int t = e >> 10, r = e & 1023;
        int slot = r >> 4, c = r & 15;
        int gy = ylo + (slot >> 3), gx = xlo + (slot & 7);
        size_t g = ((size_t)(t * HH + gy) * WWD + gx) * CCH + c * 8;
        *(uint4*)&Ks[t * KTS + slot * 136 + c * 8] = *(const uint4*)(Kb + g);
    }
    // ---- stage ALL 3 V^T tiles: 2 slots packed per b32 write (conflict-free)
#pragma unroll
    for (int i = 0; i < 6; ++i) {
        int p = i * 512 + tid;
        int t = p >> 10, r = p & 1023;
        int sp2 = r & 31, cq = r >> 5;
        int slot0 = sp2 * 2, ch0 = cq * 4;
        int gy = ylo + (slot0 >> 3), gx = xlo + (slot0 & 7);
        size_t g = ((size_t)(t * HH + gy) * WWD + gx) * CCH + ch0;
        uint2 a = *(const uint2*)(Vb + g);            // slot0  ch0..3
        uint2 b = *(const uint2*)(Vb + g + CCH);      // slot0+1 (gx+1)
        unsigned v0 = (a.x & 0xffffu) | (b.x << 16);
        unsigned v1 = (a.x >> 16)     | (b.x & 0xffff0000u);
        unsigned v2 = (a.y & 0xffffu) | (b.y << 16);
        unsigned v3 = (a.y >> 16)     | (b.y & 0xffff0000u);
        unsigned short* vt = Vt + t * VTS;
        *(unsigned*)&vt[(ch0 + 0) * 68 + slot0] = v0;
        *(unsigned*)&vt[(ch0 + 1) * 68 + slot0] = v1;
        *(unsigned*)&vt[(ch0 + 2) * 68 + slot0] = v2;
        *(unsigned*)&vt[(ch0 + 3) * 68 + slot0] = v3;
    }

    // ---- Q fragments (B operand): lane holds Q'[d = quad*4+i][q = l16]  (issues under staging)
    short4v qfr[3];
#pragma unroll
    for (int qt = 0; qt < 3; ++qt) {
        int qrow = qt * (HH * WWD) + yy * WWD + xx;
        qfr[qt] = *(const short4v*)(Qb + (size_t)qrow * CCH + h16 + quad * 4);
    }

    // ---- sp_emb A fragments (2 tiles of 16 kc-rows), double-bf16 for f32-class accuracy
    short4v sph[2], spl[2];
#pragma unroll
    for (int tile = 0; tile < 2; ++tile) {
        int kcr = min(tile * 16 + l16, 24);
        float4 v = *(const float4*)(sp_emb + (size_t)kcr * CCH + h16 + quad * 4);
        float vv[4] = {v.x, v.y, v.z, v.w};
        union { short4v s4; unsigned short u[4]; } ph, pl;
#pragma unroll
        for (int i = 0; i < 4; ++i) {
            ph.u[i] = f2bf(vv[i]);
            pl.u[i] = f2bf(vv[i] - bfu(ph.u[i]));
        }
        sph[tile] = ph.s4; spl[tile] = pl.s4;
    }

    // ---- bias[kc][q] = Q'(q) . sp_emb(kc)  via MFMA, per-wave LDS region (log2e rides on Q')
    const int bbase = w * (3 * 25 * 17);
#pragma unroll
    for (int qt = 0; qt < 3; ++qt) {
#pragma unroll
        for (int tile = 0; tile < 2; ++tile) {
            float4v d = MFMA16(spl[tile], qfr[qt], ((float4v){0.f,0.f,0.f,0.f}));
            d = MFMA16(sph[tile], qfr[qt], d);
#pragma unroll
            for (int r = 0; r < 4; ++r) {
                int kc = tile * 16 + quad * 4 + r;
                if (kc < 25) biasL[bbase + (qt * 25 + kc) * 17 + l16] = d[r];
            }
        }
    }

    // ---- per-lane score-element geometry: slot = kt*16 + quad*4 + r, query = l16
    int badr[16];
#pragma unroll
    for (int kt = 0; kt < 4; ++kt)
#pragma unroll
        for (int r = 0; r < 4; ++r) {
            int slot = kt * 16 + quad * 4 + r;
            int gy = ylo + (slot >> 3), gx = xlo + (slot & 7);
            int py = gy - yc + 2, px = gx - xc + 2;
            bool ok = (py >= 0) && (py < 5) && (px >= 0) && (px < 5);
            badr[kt * 4 + r] = ok ? (bbase + (py * 5 + px) * 17 + l16) : -1;
        }

    __syncthreads();                     // ONE barrier: all K/V tiles resident

    float m[3] = {-1e30f, -1e30f, -1e30f};
    float l[3] = {0.f, 0.f, 0.f};
    float4v oacc[3];
#pragma unroll
    for (int qt = 0; qt < 3; ++qt) oacc[qt] = (float4v){0.f,0.f,0.f,0.f};

#pragma unroll
    for (int t = 0; t < TT; ++t) {
        const unsigned short* Kc = Ks + t * KTS;
        const unsigned short* Vc = Vt + t * VTS;

        // fragment loads (shared across the 3 q-tiles); t+1's loads can issue under t's softmax
        short4v kfr[4], vfr[4];
#pragma unroll
        for (int kt = 0; kt < 4; ++kt) {
            kfr[kt] = *(const short4v*)&Kc[(kt * 16 + l16) * 136 + h16 + quad * 4];
            vfr[kt] = *(const short4v*)&Vc[(h16 + l16) * 68 + kt * 16 + quad * 4];
        }

#pragma unroll
        for (int qt = 0; qt < 3; ++qt) {
            // scores (base-2 domain) with bias+mask injected through C
            float4v s[4];
#pragma unroll
            for (int kt = 0; kt < 4; ++kt) {
                float4v c;
#pragma unroll
                for (int r = 0; r < 4; ++r) {
                    int a = badr[kt * 4 + r];
                    c[r] = (a < 0) ? -1e30f : biasL[a + qt * 425];
                }
                s[kt] = MFMA16(kfr[kt], qfr[qt], c);
            }
            // online softmax (stats in q=l16 layout; cross-quad reduce = 2 shuffles)
            float mx = m[qt];
#pragma unroll
            for (int kt = 0; kt < 4; ++kt)
#pragma unroll
                for (int r = 0; r < 4; ++r) mx = fmaxf(mx, s[kt][r]);
            mx = fmaxf(mx, __shfl_xor(mx, 16));
            mx = fmaxf(mx, __shfl_xor(mx, 32));
            float corr = exp2f(m[qt] - mx);
            m[qt] = mx;
            l[qt] *= corr;
            float4v oc = oacc[qt] * corr;
            float lsum = 0.f;
            short4v pfr[4];
#pragma unroll
            for (int kt = 0; kt < 4; ++kt) {
                float p0 = exp2f(s[kt][0] - mx), p1 = exp2f(s[kt][1] - mx);
                float p2 = exp2f(s[kt][2] - mx), p3 = exp2f(s[kt][3] - mx);
                lsum += (p0 + p1) + (p2 + p3);
                union { short4v s4; unsigned short u[4]; } pk;
                pk.u[0] = f2bf(p0); pk.u[1] = f2bf(p1);
                pk.u[2] = f2bf(p2); pk.u[3] = f2bf(p3);
                pfr[kt] = pk.s4;
            }
            l[qt] += lsum;
            // PV: O^T accumulate; score D-frag == P B-frag, V^T A-frag from LDS
#pragma unroll
            for (int kt = 0; kt < 4; ++kt) oc = MFMA16(vfr[kt], pfr[kt], oc);
            oacc[qt] = oc;
        }
    }

    // ---- epilogue part 1: normalize O, stage bf16 rows to LDS (aliases Ks)
    __syncthreads();                      // all waves done with Ks/Vt/bias reads
#pragma unroll
    for (int qt = 0; qt < 3; ++qt) {
        float lt = l[qt];
        lt += __shfl_xor(lt, 16);
        lt += __shfl_xor(lt, 32);
        float inv = 1.f / lt;
        union { ushort4 u4; unsigned short u[4]; } ob;
#pragma unroll
        for (int r = 0; r < 4; ++r) ob.u[r] = f2bf(oacc[qt][r] * inv);
        *(ushort4*)&Os[(qt * 16 + l16) * 136 + h16 + quad * 4] = ob.u4;
    }
    __syncthreads();

    // ---- epilogue part 2: fused out-proj. wave w -> out-ch slab [w*16, w*16+16); D -> OF (LDS)
    float4v pacc[3];
#pragma unroll
    for (int nt = 0; nt < 3; ++nt) pacc[nt] = (float4v){0.f, 0.f, 0.f, 0.f};
#pragma unroll
    for (int ks = 0; ks < 4; ++ks) {
        short8 bfrag[3];
#pragma unroll
        for (int nt = 0; nt < 3; ++nt)
            bfrag[nt] = *(const short8*)&Os[(nt * 16 + l16) * 136 + ks * 32 + quad * 8];
        size_t wo = (size_t)(w * 16 + l16) * CCH + ks * 32 + quad * 8;
        short8 a1 = *(const short8*)(Wo1 + wo);
        short8 a2 = *(const short8*)(Wo2 + wo);
#pragma unroll
        for (int nt = 0; nt < 3; ++nt) {
            pacc[nt] = __builtin_amdgcn_mfma_f32_16x16x32_bf16(a1, bfrag[nt], pacc[nt], 0, 0, 0);
            pacc[nt] = __builtin_amdgcn_mfma_f32_16x16x32_bf16(a2, bfrag[nt], pacc[nt], 0, 0, 0);
        }
    }
#pragma unroll
    for (int nt = 0; nt < 3; ++nt) {      // OF[(qt*16 + query)][out-ch], query = l16 (D col), ch = quad*4+r (D row)
        float4v a = pacc[nt];
        float4 o; o.x = a[0]; o.y = a[1]; o.z = a[2]; o.w = a[3];
        *(float4*)&OF[(nt * 16 + l16) * 132 + w * 16 + quad * 4] = o;
    }
    __syncthreads();

    // ---- epilogue part 3: cooperative fully-coalesced copy OF -> out
    for (int i = tid; i < 1536; i += 512) {
        int cy = i / 384;                 // chunk
        int r  = i - cy * 384;            // float4 index within chunk (0..383)
        int row12 = r >> 5;               // 0..11 = cx*3 + nt
        int ch    = (r & 31) * 4;
        int cx = row12 / 3, nt = row12 - cx * 3;
        float4 v = *(const float4*)&OF[(nt * 16 + cy * 4 + cx) * 132 + ch];
        size_t g = ((size_t)((y0 + cy) * WWD + x0) * TT) * CCH + r * 4;
        *(float4*)(out + g) = v;
    }
}

extern "C" void kernel_launch(void* const* d_in, const int* in_sizes, int n_in,
                              void* d_out, int out_size, void* d_ws, size_t ws_size,
                              hipStream_t stream) {
    const float* x        = (const float*)d_in[0];
    const float* Wq       = (const float*)d_in[1];
    const float* Wk       = (const float*)d_in[2];
    const float* Wv       = (const float*)d_in[3];
    const float* Wo       = (const float*)d_in[4];
    const float* temp_emb = (const float*)d_in[5];
    const float* sp_emb   = (const float*)d_in[6];
    float* out = (float*)d_out;

    const size_t nb = (size_t)NROWS * CCH * 2;   // bytes per bf16 buffer
    unsigned short* Qb  = (unsigned short*)d_ws;
    unsigned short* Kb  = (unsigned short*)((char*)d_ws + nb);
    unsigned short* Vb  = (unsigned short*)((char*)d_ws + 2 * nb);
    unsigned short* Wt  = (unsigned short*)((char*)d_ws + 3 * nb);
    unsigned short* Wo1 = Wt + 384 * 128;
    unsigned short* Wo2 = Wo1 + 128 * 128;

    prep_kernel<<<64, 256, 0, stream>>>(Wq, Wk, Wv, Wo, Wt, Wo1, Wo2);
    qkv_kernel<<<NROWS / 64, 512, 0, stream>>>(x, Wt, temp_emb, sp_emb, Qb, Kb, Vb);
    attn_kernel<<<(HH / PX) * (WWD / PX), 512, 0, stream>>>(Qb, Kb, Vb, sp_emb, Wo1, Wo2, out);
}

// Round 14
// 138.753 us; speedup vs baseline: 1.0290x; 1.0290x over previous
//
#include <hip/hip_runtime.h>
#include <hip/hip_bf16.h>
#include <math.h>

#define TT 3
#define HH 96
#define WWD 96
#define CCH 128
#define NROWS (TT*HH*WWD)   // 27648

typedef __attribute__((ext_vector_type(8))) short short8;
typedef __attribute__((ext_vector_type(4))) short short4v;
typedef __attribute__((ext_vector_type(4))) float float4v;

__device__ __forceinline__ float bfu(unsigned short u){ union{unsigned u;float f;}c; c.u=((unsigned)u)<<16; return c.f; }
__device__ __forceinline__ unsigned short f2bf(float f){ __hip_bfloat16 h=__float2bfloat16(f); return *(unsigned short*)&h; }

// ---- 16x16x16 bf16 MFMA (K = d_head = 16) ----
#if defined(__has_builtin)
#if __has_builtin(__builtin_amdgcn_mfma_f32_16x16x16bf16_1k)
#define MFMA16(A,B,C) __builtin_amdgcn_mfma_f32_16x16x16bf16_1k(A,B,C,0,0,0)
#endif
#endif
#ifndef MFMA16
static __device__ __forceinline__ float4v mfma16_asm(short4v a, short4v b, float4v c){
    float4v d;
    asm("v_mfma_f32_16x16x16_bf16 %0, %1, %2, %3" : "=v"(d) : "v"(a), "v"(b), "v"(c));
    return d;
}
#define MFMA16(A,B,C) mfma16_asm(A,B,C)
#endif

// Q pre-scale: 1/sqrt(16) * log2(e)  -> scores live in base-2 domain, exp() becomes native v_exp_f32
#define QSCL 0.36067376022224085f

// ---------------- Kernel 0: weight prep, LDS-tile transpose (coalesced both sides) ----------------
__launch_bounds__(256)
__global__ void prep_kernel(const float* __restrict__ Wq, const float* __restrict__ Wk,
                            const float* __restrict__ Wv, const float* __restrict__ Wo,
                            unsigned short* __restrict__ Wt, unsigned short* __restrict__ Wo1,
                            unsigned short* __restrict__ Wo2) {
    __shared__ float ts[32][33];
    const int m = blockIdx.x >> 4, tile = blockIdx.x & 15;
    const int k0 = (tile >> 2) * 32, n0 = (tile & 3) * 32;
    const float* src = (m == 0) ? Wq : (m == 1) ? Wk : (m == 2) ? Wv : Wo;
    const int tid = threadIdx.x;
    const int c = tid & 31, r8 = tid >> 5;
#pragma unroll
    for (int rr = 0; rr < 4; ++rr) {
        int r = r8 * 4 + rr;
        ts[r][c] = src[(size_t)(k0 + r) * 128 + n0 + c];
    }
    __syncthreads();
#pragma unroll
    for (int rr = 0; rr < 4; ++rr) {
        int r = r8 * 4 + rr;
        float v = ts[c][r];
        if (m < 3) {
            Wt[(size_t)(m * 128 + n0 + r) * 128 + k0 + c] = f2bf(v);
        } else {
            unsigned short w1 = f2bf(v);
            Wo1[(size_t)(n0 + r) * 128 + k0 + c] = w1;
            Wo2[(size_t)(n0 + r) * 128 + k0 + c] = f2bf(v - bfu(w1));
        }
    }
}

// ---------------- Kernel 1: QKV projection, M-tile 64, mt==matrix mapping, LDS coalesced epilogue ----
__launch_bounds__(512)
__global__ void qkv_kernel(const float* __restrict__ x,
                           const unsigned short* __restrict__ Wt,
                           const float* __restrict__ temp_emb,
                           const float* __restrict__ sp_emb,
                           unsigned short* __restrict__ Qb,
                           unsigned short* __restrict__ Kb,
                           unsigned short* __restrict__ Vb) {
    // [0,17408) xs bf16 [64][136]  |  epilogue alias: OF f32 [64][132] = 33792 B
    __shared__ __align__(16) char smem[33792];
    unsigned short* xs = (unsigned short*)smem;
    float* OF          = (float*)smem;

    const int tid = threadIdx.x;
    const int q0 = blockIdx.x * 64;
    const int t = q0 / (HH * WWD);               // uniform per block

    for (int e = tid; e < 2048; e += 512) {
        int row = e >> 5, col = (e & 31) * 4;
        float4 v = *(const float4*)(x + (size_t)(q0 + row) * CCH + col);
        ushort4 u; u.x = f2bf(v.x); u.y = f2bf(v.y); u.z = f2bf(v.z); u.w = f2bf(v.w);
        *(ushort4*)&xs[row * 136 + col] = u;
    }
    __syncthreads();

    const int w = tid >> 6, lane = tid & 63, quad = lane >> 4, l16 = lane & 15;

    float4v acc[3][4];
#pragma unroll
    for (int m = 0; m < 3; ++m)
#pragma unroll
        for (int nt = 0; nt < 4; ++nt) acc[m][nt] = (float4v){0,0,0,0};

#pragma unroll
    for (int ks = 0; ks < 4; ++ks) {
        short8 b[4];
#pragma unroll
        for (int nt = 0; nt < 4; ++nt)
            b[nt] = *(const short8*)&xs[(nt * 16 + l16) * 136 + ks * 32 + quad * 8];
#pragma unroll
        for (int m = 0; m < 3; ++m) {
            short8 a = *(const short8*)(Wt + (size_t)(m * 128 + w * 16 + l16) * CCH + ks * 32 + quad * 8);
#pragma unroll
            for (int nt = 0; nt < 4; ++nt)
                acc[m][nt] = __builtin_amdgcn_mfma_f32_16x16x32_bf16(a, b[nt], acc[m][nt], 0, 0, 0);
        }
    }

    unsigned short* dst[3] = {Qb, Kb, Vb};
#pragma unroll
    for (int m = 0; m < 3; ++m) {
        __syncthreads();
#pragma unroll
        for (int nt = 0; nt < 4; ++nt) {
            float4v a = acc[m][nt];
            float4 o; o.x = a[0]; o.y = a[1]; o.z = a[2]; o.w = a[3];
            *(float4*)&OF[(nt * 16 + l16) * 132 + w * 16 + quad * 4] = o;
        }
        __syncthreads();
        for (int e = tid; e < 2048; e += 512) {
            int row = e >> 5, c4 = (e & 31);
            int ch = c4 * 4;
            float4 v = *(const float4*)&OF[row * 132 + ch];
            int q = q0 + row;
            ushort4 u;
            if (m == 0) {
                int rem = q - t * (HH * WWD);
                int yy = rem / WWD, xx = rem - (rem / WWD) * WWD;
                int qidx = (yy - min(max(yy, 2), 93) + 2) * 5 + (xx - min(max(xx, 2), 93) + 2);
                float4 te = *(const float4*)(temp_emb + t * CCH + ch);
                float4 se = *(const float4*)(sp_emb + qidx * CCH + ch);
                u.x = f2bf((v.x + te.x + se.x) * QSCL);
                u.y = f2bf((v.y + te.y + se.y) * QSCL);
                u.z = f2bf((v.z + te.z + se.z) * QSCL);
                u.w = f2bf((v.w + te.w + se.w) * QSCL);
            } else if (m == 1) {
                float4 te = *(const float4*)(temp_emb + t * CCH + ch);
                u.x = f2bf(v.x + te.x); u.y = f2bf(v.y + te.y);
                u.z = f2bf(v.z + te.z); u.w = f2bf(v.w + te.w);
            } else {
                u.x = f2bf(v.x); u.y = f2bf(v.y); u.z = f2bf(v.z); u.w = f2bf(v.w);
            }
            *(ushort4*)(dst[m] + (size_t)q * CCH + ch) = u;
        }
    }
}

// ---------------- Kernel 2: MFMA flash attention (R12 optimum) + V^T stride-70 conflict fix ----------------
// Block = 4x4 spatial patch. 512 thr = 8 waves, wave = head. exp2 domain, XCD swizzle, VGPR 64.
// R14: V^T channel stride 68 -> 70 ushorts. At stride 68, vfr reads hit bank (2*l16+2*quad+C)%32:
// lanes with equal l16+quad collide -> 4-way conflict (1.58x, m136). Stride 70 gives
// (3*l16+2*quad+C)%32 -> <=2-way (free). Staging writes stay conflict-free (35*ch+sp2).
#define PX 4
#define WIN 8
#define VSTR 70

__launch_bounds__(512, 4)
__global__ void attn_kernel(const unsigned short* __restrict__ Qb,
                            const unsigned short* __restrict__ Kb,
                            const unsigned short* __restrict__ Vb,
                            const float* __restrict__ sp_emb,
                            const unsigned short* __restrict__ Wo1,
                            const unsigned short* __restrict__ Wo2,
                            float* __restrict__ out) {
    // [0,17408)        K tile  [64][136] ushort      | epilogue: Os bf16 [48][136] (13056 B)
    // [17408,35328)    V^T     [128][70] ushort
    // [35328,76128)    bias f32 [8][3][25][17]       | epilogue: OF f32 [48][132] (25344 B)
    __shared__ __align__(16) char smem[76128];
    unsigned short* Ks = (unsigned short*)smem;
    unsigned short* Vt = (unsigned short*)(smem + 17408);
    float* biasL       = (float*)(smem + 35328);
    unsigned short* Os = (unsigned short*)smem;
    float* OF          = (float*)(smem + 35328);

    const int tid = threadIdx.x;
    const int lane = tid & 63;
    const int w = tid >> 6;                      // head
    const int quad = lane >> 4, l16 = lane & 15;
    const int h16 = w * 16;

    // XCD-aware bijective swizzle: 576 blocks, 8 XCDs, 72 contiguous patches per XCD
    const int wg = (blockIdx.x & 7) * (576 / 8) + (blockIdx.x >> 3);
    const int bx = wg % (WWD / PX);
    const int by = wg / (WWD / PX);
    const int x0 = bx * PX, y0 = by * PX;
    const int xlo = min(max(x0 - 2, 0), WWD - WIN);
    const int ylo = min(max(y0 - 2, 0), HH - WIN);

    const int qdy = l16 >> 2, qdx = l16 & 3;
    const int yy = y0 + qdy, xx = x0 + qdx;
    const int yc = min(max(yy, 2), HH - 3), xc = min(max(xx, 2), WWD - 3);

    // ---- Q fragments (B operand): lane holds Q'[d = quad*4+i][q = l16]
    short4v qfr[3];
#pragma unroll
    for (int qt = 0; qt < 3; ++qt) {
        int qrow = qt * (HH * WWD) + yy * WWD + xx;
        qfr[qt] = *(const short4v*)(Qb + (size_t)qrow * CCH + h16 + quad * 4);
    }

    // ---- sp_emb A fragments (2 tiles of 16 kc-rows), double-bf16 for f32-class accuracy
    short4v sph[2], spl[2];
#pragma unroll
    for (int tile = 0; tile < 2; ++tile) {
        int kcr = min(tile * 16 + l16, 24);
        float4 v = *(const float4*)(sp_emb + (size_t)kcr * CCH + h16 + quad * 4);
        float vv[4] = {v.x, v.y, v.z, v.w};
        union { short4v s4; unsigned short u[4]; } ph, pl;
#pragma unroll
        for (int i = 0; i < 4; ++i) {
            ph.u[i] = f2bf(vv[i]);
            pl.u[i] = f2bf(vv[i] - bfu(ph.u[i]));
        }
        sph[tile] = ph.s4; spl[tile] = pl.s4;
    }

    // ---- bias[kc][q] = Q'(q) . sp_emb(kc)  via MFMA, per-wave LDS region (log2e rides on Q')
    const int bbase = w * (3 * 25 * 17);
#pragma unroll
    for (int qt = 0; qt < 3; ++qt) {
#pragma unroll
        for (int tile = 0; tile < 2; ++tile) {
            float4v d = MFMA16(spl[tile], qfr[qt], ((float4v){0.f,0.f,0.f,0.f}));
            d = MFMA16(sph[tile], qfr[qt], d);
#pragma unroll
            for (int r = 0; r < 4; ++r) {
                int kc = tile * 16 + quad * 4 + r;
                if (kc < 25) biasL[bbase + (qt * 25 + kc) * 17 + l16] = d[r];
            }
        }
    }

    // ---- per-lane score-element geometry: slot = kt*16 + quad*4 + r, query = l16
    int badr[16];
#pragma unroll
    for (int kt = 0; kt < 4; ++kt)
#pragma unroll
        for (int r = 0; r < 4; ++r) {
            int slot = kt * 16 + quad * 4 + r;
            int gy = ylo + (slot >> 3), gx = xlo + (slot & 7);
            int py = gy - yc + 2, px = gx - xc + 2;
            bool ok = (py >= 0) && (py < 5) && (px >= 0) && (px < 5);
            badr[kt * 4 + r] = ok ? (bbase + (py * 5 + px) * 17 + l16) : -1;
        }

    float m[3] = {-1e30f, -1e30f, -1e30f};
    float l[3] = {0.f, 0.f, 0.f};
    float4v oacc[3];
#pragma unroll
    for (int qt = 0; qt < 3; ++qt) oacc[qt] = (float4v){0.f,0.f,0.f,0.f};

    for (int t = 0; t < TT; ++t) {
        __syncthreads();
        // stage K tile [slot][128] (coalesced uint4)
        for (int e = tid; e < 1024; e += 512) {
            int slot = e >> 4, c = e & 15;
            int gy = ylo + (slot >> 3), gx = xlo + (slot & 7);
            size_t g = ((size_t)(t * HH + gy) * WWD + gx) * CCH + c * 8;
            *(uint4*)&Ks[slot * 136 + c * 8] = *(const uint4*)(Kb + g);
        }
        // stage V transposed [ch][slot]: 2 slots packed per b32 write (conflict-free: 35*ch+sp2)
        for (int p = tid; p < 1024; p += 512) {
            int sp2 = p & 31, cq = p >> 5;
            int slot0 = sp2 * 2, ch0 = cq * 4;
            int gy = ylo + (slot0 >> 3), gx = xlo + (slot0 & 7);
            size_t g = ((size_t)(t * HH + gy) * WWD + gx) * CCH + ch0;
            uint2 a = *(const uint2*)(Vb + g);            // slot0  ch0..3
            uint2 b = *(const uint2*)(Vb + g + CCH);      // slot0+1 (gx+1)
            unsigned v0 = (a.x & 0xffffu) | (b.x << 16);
            unsigned v1 = (a.x >> 16)     | (b.x & 0xffff0000u);
            unsigned v2 = (a.y & 0xffffu) | (b.y << 16);
            unsigned v3 = (a.y >> 16)     | (b.y & 0xffff0000u);
            *(unsigned*)&Vt[(ch0 + 0) * VSTR + slot0] = v0;
            *(unsigned*)&Vt[(ch0 + 1) * VSTR + slot0] = v1;
            *(unsigned*)&Vt[(ch0 + 2) * VSTR + slot0] = v2;
            *(unsigned*)&Vt[(ch0 + 3) * VSTR + slot0] = v3;
        }
        __syncthreads();

        // fragment loads (shared across the 3 q-tiles)
        short4v kfr[4], vfr[4];
#pragma unroll
        for (int kt = 0; kt < 4; ++kt) {
            kfr[kt] = *(const short4v*)&Ks[(kt * 16 + l16) * 136 + h16 + quad * 4];
            vfr[kt] = *(const short4v*)&Vt[(h16 + l16) * VSTR + kt * 16 + quad * 4];
        }

#pragma unroll
        for (int qt = 0; qt < 3; ++qt) {
            // scores (base-2 domain) with bias+mask injected through C
            float4v s[4];
#pragma unroll
            for (int kt = 0; kt < 4; ++kt) {
                float4v c;
#pragma unroll
                for (int r = 0; r < 4; ++r) {
                    int a = badr[kt * 4 + r];
                    c[r] = (a < 0) ? -1e30f : biasL[a + qt * 425];
                }
                s[kt] = MFMA16(kfr[kt], qfr[qt], c);
            }
            // online softmax (stats in q=l16 layout; cross-quad reduce = 2 shuffles)
            float mx = m[qt];
#pragma unroll
            for (int kt = 0; kt < 4; ++kt)
#pragma unroll
                for (int r = 0; r < 4; ++r) mx = fmaxf(mx, s[kt][r]);
            mx = fmaxf(mx, __shfl_xor(mx, 16));
            mx = fmaxf(mx, __shfl_xor(mx, 32));
            float corr = exp2f(m[qt] - mx);
            m[qt] = mx;
            l[qt] *= corr;
            float4v oc = oacc[qt] * corr;
            float lsum = 0.f;
            short4v pfr[4];
#pragma unroll
            for (int kt = 0; kt < 4; ++kt) {
                float p0 = exp2f(s[kt][0] - mx), p1 = exp2f(s[kt][1] - mx);
                float p2 = exp2f(s[kt][2] - mx), p3 = exp2f(s[kt][3] - mx);
                lsum += (p0 + p1) + (p2 + p3);
                union { short4v s4; unsigned short u[4]; } pk;
                pk.u[0] = f2bf(p0); pk.u[1] = f2bf(p1);
                pk.u[2] = f2bf(p2); pk.u[3] = f2bf(p3);
                pfr[kt] = pk.s4;
            }
            l[qt] += lsum;
            // PV: O^T accumulate; score D-frag == P B-frag, V^T A-frag from LDS
#pragma unroll
            for (int kt = 0; kt < 4; ++kt) oc = MFMA16(vfr[kt], pfr[kt], oc);
            oacc[qt] = oc;
        }
    }

    // ---- epilogue part 1: normalize O, stage bf16 rows to LDS (aliases Ks)
    __syncthreads();                      // all waves done with Ks/Vt/bias reads
#pragma unroll
    for (int qt = 0; qt < 3; ++qt) {
        float lt = l[qt];
        lt += __shfl_xor(lt, 16);
        lt += __shfl_xor(lt, 32);
        float inv = 1.f / lt;
        union { ushort4 u4; unsigned short u[4]; } ob;
#pragma unroll
        for (int r = 0; r < 4; ++r) ob.u[r] = f2bf(oacc[qt][r] * inv);
        *(ushort4*)&Os[(qt * 16 + l16) * 136 + h16 + quad * 4] = ob.u4;
    }
    __syncthreads();

    // ---- epilogue part 2: fused out-proj. wave w -> out-ch slab [w*16, w*16+16); D -> OF (LDS)
    float4v pacc[3];
#pragma unroll
    for (int nt = 0; nt < 3; ++nt) pacc[nt] = (float4v){0.f, 0.f, 0.f, 0.f};
#pragma unroll
    for (int ks = 0; ks < 4; ++ks) {
        short8 bfrag[3];
#pragma unroll
        for (int nt = 0; nt < 3; ++nt)
            bfrag[nt] = *(const short8*)&Os[(nt * 16 + l16) * 136 + ks * 32 + quad * 8];
        size_t wo = (size_t)(w * 16 + l16) * CCH + ks * 32 + quad * 8;
        short8 a1 = *(const short8*)(Wo1 + wo);
        short8 a2 = *(const short8*)(Wo2 + wo);
#pragma unroll
        for (int nt = 0; nt < 3; ++nt) {
            pacc[nt] = __builtin_amdgcn_mfma_f32_16x16x32_bf16(a1, bfrag[nt], pacc[nt], 0, 0, 0);
            pacc[nt] = __builtin_amdgcn_mfma_f32_16x16x32_bf16(a2, bfrag[nt], pacc[nt], 0, 0, 0);
        }
    }
#pragma unroll
    for (int nt = 0; nt < 3; ++nt) {      // OF[(qt*16 + query)][out-ch], query = l16 (D col), ch = quad*4+r (D row)
        float4v a = pacc[nt];
        float4 o; o.x = a[0]; o.y = a[1]; o.z = a[2]; o.w = a[3];
        *(float4*)&OF[(nt * 16 + l16) * 132 + w * 16 + quad * 4] = o;
    }
    __syncthreads();

    // ---- epilogue part 3: cooperative fully-coalesced copy OF -> out
    for (int i = tid; i < 1536; i += 512) {
        int cy = i / 384;                 // chunk
        int r  = i - cy * 384;            // float4 index within chunk (0..383)
        int row12 = r >> 5;               // 0..11 = cx*3 + nt
        int ch    = (r & 31) * 4;
        int cx = row12 / 3, nt = row12 - cx * 3;
        float4 v = *(const float4*)&OF[(nt * 16 + cy * 4 + cx) * 132 + ch];
        size_t g = ((size_t)((y0 + cy) * WWD + x0) * TT) * CCH + r * 4;
        *(float4*)(out + g) = v;
    }
}

extern "C" void kernel_launch(void* const* d_in, const int* in_sizes, int n_in,
                              void* d_out, int out_size, void* d_ws, size_t ws_size,
                              hipStream_t stream) {
    const float* x        = (const float*)d_in[0];
    const float* Wq       = (const float*)d_in[1];
    const float* Wk       = (const float*)d_in[2];
    const float* Wv       = (const float*)d_in[3];
    const float* Wo       = (const float*)d_in[4];
    const float* temp_emb = (const float*)d_in[5];
    const float* sp_emb   = (const float*)d_in[6];
    float* out = (float*)d_out;

    const size_t nb = (size_t)NROWS * CCH * 2;   // bytes per bf16 buffer
    unsigned short* Qb  = (unsigned short*)d_ws;
    unsigned short* Kb  = (unsigned short*)((char*)d_ws + nb);
    unsigned short* Vb  = (unsigned short*)((char*)d_ws + 2 * nb);
    unsigned short* Wt  = (unsigned short*)((char*)d_ws + 3 * nb);
    unsigned short* Wo1 = Wt + 384 * 128;
    unsigned short* Wo2 = Wo1 + 128 * 128;

    prep_kernel<<<64, 256, 0, stream>>>(Wq, Wk, Wv, Wo, Wt, Wo1, Wo2);
    qkv_kernel<<<NROWS / 64, 512, 0, stream>>>(x, Wt, temp_emb, sp_emb, Qb, Kb, Vb);
    attn_kernel<<<(HH / PX) * (WWD / PX), 512, 0, stream>>>(Qb, Kb, Vb, sp_emb, Wo1, Wo2, out);
}

// Round 15
// 130.988 us; speedup vs baseline: 1.0900x; 1.0593x over previous
//
#include <hip/hip_runtime.h>
#include <hip/hip_bf16.h>
#include <math.h>

#define TT 3
#define HH 96
#define WWD 96
#define CCH 128
#define NROWS (TT*HH*WWD)   // 27648

typedef __attribute__((ext_vector_type(8))) short short8;
typedef __attribute__((ext_vector_type(4))) short short4v;
typedef __attribute__((ext_vector_type(4))) float float4v;

__device__ __forceinline__ float bfu(unsigned short u){ union{unsigned u;float f;}c; c.u=((unsigned)u)<<16; return c.f; }
__device__ __forceinline__ unsigned short f2bf(float f){ __hip_bfloat16 h=__float2bfloat16(f); return *(unsigned short*)&h; }

// ---- 16x16x16 bf16 MFMA (K = d_head = 16) ----
#if defined(__has_builtin)
#if __has_builtin(__builtin_amdgcn_mfma_f32_16x16x16bf16_1k)
#define MFMA16(A,B,C) __builtin_amdgcn_mfma_f32_16x16x16bf16_1k(A,B,C,0,0,0)
#endif
#endif
#ifndef MFMA16
static __device__ __forceinline__ float4v mfma16_asm(short4v a, short4v b, float4v c){
    float4v d;
    asm("v_mfma_f32_16x16x16_bf16 %0, %1, %2, %3" : "=v"(d) : "v"(a), "v"(b), "v"(c));
    return d;
}
#define MFMA16(A,B,C) mfma16_asm(A,B,C)
#endif

// Q pre-scale: 1/sqrt(16) * log2(e)  -> scores live in base-2 domain, exp() becomes native v_exp_f32
#define QSCL 0.36067376022224085f

// ---------------- Kernel 0: weight prep, LDS-tile transpose (coalesced both sides) ----------------
__launch_bounds__(256)
__global__ void prep_kernel(const float* __restrict__ Wq, const float* __restrict__ Wk,
                            const float* __restrict__ Wv, const float* __restrict__ Wo,
                            unsigned short* __restrict__ Wt, unsigned short* __restrict__ Wo1,
                            unsigned short* __restrict__ Wo2) {
    __shared__ float ts[32][33];
    const int m = blockIdx.x >> 4, tile = blockIdx.x & 15;
    const int k0 = (tile >> 2) * 32, n0 = (tile & 3) * 32;
    const float* src = (m == 0) ? Wq : (m == 1) ? Wk : (m == 2) ? Wv : Wo;
    const int tid = threadIdx.x;
    const int c = tid & 31, r8 = tid >> 5;
#pragma unroll
    for (int rr = 0; rr < 4; ++rr) {
        int r = r8 * 4 + rr;
        ts[r][c] = src[(size_t)(k0 + r) * 128 + n0 + c];
    }
    __syncthreads();
#pragma unroll
    for (int rr = 0; rr < 4; ++rr) {
        int r = r8 * 4 + rr;
        float v = ts[c][r];
        if (m < 3) {
            Wt[(size_t)(m * 128 + n0 + r) * 128 + k0 + c] = f2bf(v);
        } else {
            unsigned short w1 = f2bf(v);
            Wo1[(size_t)(n0 + r) * 128 + k0 + c] = w1;
            Wo2[(size_t)(n0 + r) * 128 + k0 + c] = f2bf(v - bfu(w1));
        }
    }
}

// ---------------- Kernel 1: QKV projection, M-tile 64, mt==matrix mapping, LDS coalesced epilogue ----
__launch_bounds__(512)
__global__ void qkv_kernel(const float* __restrict__ x,
                           const unsigned short* __restrict__ Wt,
                           const float* __restrict__ temp_emb,
                           const float* __restrict__ sp_emb,
                           unsigned short* __restrict__ Qb,
                           unsigned short* __restrict__ Kb,
                           unsigned short* __restrict__ Vb) {
    // [0,17408) xs bf16 [64][136]  |  epilogue alias: OF f32 [64][132] = 33792 B
    __shared__ __align__(16) char smem[33792];
    unsigned short* xs = (unsigned short*)smem;
    float* OF          = (float*)smem;

    const int tid = threadIdx.x;
    const int q0 = blockIdx.x * 64;
    const int t = q0 / (HH * WWD);               // uniform per block

    for (int e = tid; e < 2048; e += 512) {
        int row = e >> 5, col = (e & 31) * 4;
        float4 v = *(const float4*)(x + (size_t)(q0 + row) * CCH + col);
        ushort4 u; u.x = f2bf(v.x); u.y = f2bf(v.y); u.z = f2bf(v.z); u.w = f2bf(v.w);
        *(ushort4*)&xs[row * 136 + col] = u;
    }
    __syncthreads();

    const int w = tid >> 6, lane = tid & 63, quad = lane >> 4, l16 = lane & 15;

    float4v acc[3][4];
#pragma unroll
    for (int m = 0; m < 3; ++m)
#pragma unroll
        for (int nt = 0; nt < 4; ++nt) acc[m][nt] = (float4v){0,0,0,0};

#pragma unroll
    for (int ks = 0; ks < 4; ++ks) {
        short8 b[4];
#pragma unroll
        for (int nt = 0; nt < 4; ++nt)
            b[nt] = *(const short8*)&xs[(nt * 16 + l16) * 136 + ks * 32 + quad * 8];
#pragma unroll
        for (int m = 0; m < 3; ++m) {
            short8 a = *(const short8*)(Wt + (size_t)(m * 128 + w * 16 + l16) * CCH + ks * 32 + quad * 8);
#pragma unroll
            for (int nt = 0; nt < 4; ++nt)
                acc[m][nt] = __builtin_amdgcn_mfma_f32_16x16x32_bf16(a, b[nt], acc[m][nt], 0, 0, 0);
        }
    }

    unsigned short* dst[3] = {Qb, Kb, Vb};
#pragma unroll
    for (int m = 0; m < 3; ++m) {
        __syncthreads();
#pragma unroll
        for (int nt = 0; nt < 4; ++nt) {
            float4v a = acc[m][nt];
            float4 o; o.x = a[0]; o.y = a[1]; o.z = a[2]; o.w = a[3];
            *(float4*)&OF[(nt * 16 + l16) * 132 + w * 16 + quad * 4] = o;
        }
        __syncthreads();
        for (int e = tid; e < 2048; e += 512) {
            int row = e >> 5, c4 = (e & 31);
            int ch = c4 * 4;
            float4 v = *(const float4*)&OF[row * 132 + ch];
            int q = q0 + row;
            ushort4 u;
            if (m == 0) {
                int rem = q - t * (HH * WWD);
                int yy = rem / WWD, xx = rem - (rem / WWD) * WWD;
                int qidx = (yy - min(max(yy, 2), 93) + 2) * 5 + (xx - min(max(xx, 2), 93) + 2);
                float4 te = *(const float4*)(temp_emb + t * CCH + ch);
                float4 se = *(const float4*)(sp_emb + qidx * CCH + ch);
                u.x = f2bf((v.x + te.x + se.x) * QSCL);
                u.y = f2bf((v.y + te.y + se.y) * QSCL);
                u.z = f2bf((v.z + te.z + se.z) * QSCL);
                u.w = f2bf((v.w + te.w + se.w) * QSCL);
            } else if (m == 1) {
                float4 te = *(const float4*)(temp_emb + t * CCH + ch);
                u.x = f2bf(v.x + te.x); u.y = f2bf(v.y + te.y);
                u.z = f2bf(v.z + te.z); u.w = f2bf(v.w + te.w);
            } else {
                u.x = f2bf(v.x); u.y = f2bf(v.y); u.z = f2bf(v.z); u.w = f2bf(v.w);
            }
            *(ushort4*)(dst[m] + (size_t)q * CCH + ch) = u;
        }
    }
}

// ---------------- Kernel 2: MFMA flash attention (verified optimum: exp2 + XCD swizzle) ----------------
// Block = 4x4 spatial patch. 512 thr = 8 waves, wave = head. VGPR 64 (8-wave/SIMD headroom is
// load-bearing: R11 showed VGPR 112 drops residency 24->15% and costs +12us). Bias stays in LDS
// (R4/R10/R11: hoisting loses via spill or residency). V^T stride stays 68 (R14: stride 70 broke
// 8B alignment of b64 frag reads, +8us; conflict count proved V-reads aren't the conflict source).
#define PX 4
#define WIN 8

__launch_bounds__(512, 4)
__global__ void attn_kernel(const unsigned short* __restrict__ Qb,
                            const unsigned short* __restrict__ Kb,
                            const unsigned short* __restrict__ Vb,
                            const float* __restrict__ sp_emb,
                            const unsigned short* __restrict__ Wo1,
                            const unsigned short* __restrict__ Wo2,
                            float* __restrict__ out) {
    // [0,17408)        K tile  [64][136] ushort      | epilogue: Os bf16 [48][136] (13056 B)
    // [17408,34816)    V^T     [128][68] ushort
    // [34816,75616)    bias f32 [8][3][25][17]       | epilogue: OF f32 [48][132] (25344 B)
    __shared__ __align__(16) char smem[75616];
    unsigned short* Ks = (unsigned short*)smem;
    unsigned short* Vt = (unsigned short*)(smem + 17408);
    float* biasL       = (float*)(smem + 34816);
    unsigned short* Os = (unsigned short*)smem;
    float* OF          = (float*)(smem + 34816);

    const int tid = threadIdx.x;
    const int lane = tid & 63;
    const int w = tid >> 6;                      // head
    const int quad = lane >> 4, l16 = lane & 15;
    const int h16 = w * 16;

    // XCD-aware bijective swizzle: 576 blocks, 8 XCDs, 72 contiguous patches per XCD
    const int wg = (blockIdx.x & 7) * (576 / 8) + (blockIdx.x >> 3);
    const int bx = wg % (WWD / PX);
    const int by = wg / (WWD / PX);
    const int x0 = bx * PX, y0 = by * PX;
    const int xlo = min(max(x0 - 2, 0), WWD - WIN);
    const int ylo = min(max(y0 - 2, 0), HH - WIN);

    const int qdy = l16 >> 2, qdx = l16 & 3;
    const int yy = y0 + qdy, xx = x0 + qdx;
    const int yc = min(max(yy, 2), HH - 3), xc = min(max(xx, 2), WWD - 3);

    // ---- Q fragments (B operand): lane holds Q'[d = quad*4+i][q = l16]
    short4v qfr[3];
#pragma unroll
    for (int qt = 0; qt < 3; ++qt) {
        int qrow = qt * (HH * WWD) + yy * WWD + xx;
        qfr[qt] = *(const short4v*)(Qb + (size_t)qrow * CCH + h16 + quad * 4);
    }

    // ---- sp_emb A fragments (2 tiles of 16 kc-rows), double-bf16 for f32-class accuracy
    short4v sph[2], spl[2];
#pragma unroll
    for (int tile = 0; tile < 2; ++tile) {
        int kcr = min(tile * 16 + l16, 24);
        float4 v = *(const float4*)(sp_emb + (size_t)kcr * CCH + h16 + quad * 4);
        float vv[4] = {v.x, v.y, v.z, v.w};
        union { short4v s4; unsigned short u[4]; } ph, pl;
#pragma unroll
        for (int i = 0; i < 4; ++i) {
            ph.u[i] = f2bf(vv[i]);
            pl.u[i] = f2bf(vv[i] - bfu(ph.u[i]));
        }
        sph[tile] = ph.s4; spl[tile] = pl.s4;
    }

    // ---- bias[kc][q] = Q'(q) . sp_emb(kc)  via MFMA, per-wave LDS region (log2e rides on Q')
    const int bbase = w * (3 * 25 * 17);
#pragma unroll
    for (int qt = 0; qt < 3; ++qt) {
#pragma unroll
        for (int tile = 0; tile < 2; ++tile) {
            float4v d = MFMA16(spl[tile], qfr[qt], ((float4v){0.f,0.f,0.f,0.f}));
            d = MFMA16(sph[tile], qfr[qt], d);
#pragma unroll
            for (int r = 0; r < 4; ++r) {
                int kc = tile * 16 + quad * 4 + r;
                if (kc < 25) biasL[bbase + (qt * 25 + kc) * 17 + l16] = d[r];
            }
        }
    }

    // ---- per-lane score-element geometry: slot = kt*16 + quad*4 + r, query = l16
    int badr[16];
#pragma unroll
    for (int kt = 0; kt < 4; ++kt)
#pragma unroll
        for (int r = 0; r < 4; ++r) {
            int slot = kt * 16 + quad * 4 + r;
            int gy = ylo + (slot >> 3), gx = xlo + (slot & 7);
            int py = gy - yc + 2, px = gx - xc + 2;
            bool ok = (py >= 0) && (py < 5) && (px >= 0) && (px < 5);
            badr[kt * 4 + r] = ok ? (bbase + (py * 5 + px) * 17 + l16) : -1;
        }

    float m[3] = {-1e30f, -1e30f, -1e30f};
    float l[3] = {0.f, 0.f, 0.f};
    float4v oacc[3];
#pragma unroll
    for (int qt = 0; qt < 3; ++qt) oacc[qt] = (float4v){0.f,0.f,0.f,0.f};

    for (int t = 0; t < TT; ++t) {
        __syncthreads();
        // stage K tile [slot][128] (coalesced uint4)
        for (int e = tid; e < 1024; e += 512) {
            int slot = e >> 4, c = e & 15;
            int gy = ylo + (slot >> 3), gx = xlo + (slot & 7);
            size_t g = ((size_t)(t * HH + gy) * WWD + gx) * CCH + c * 8;
            *(uint4*)&Ks[slot * 136 + c * 8] = *(const uint4*)(Kb + g);
        }
        // stage V transposed [ch][slot]: 2 slots packed per b32 write (conflict-free)
        for (int p = tid; p < 1024; p += 512) {
            int sp2 = p & 31, cq = p >> 5;
            int slot0 = sp2 * 2, ch0 = cq * 4;
            int gy = ylo + (slot0 >> 3), gx = xlo + (slot0 & 7);
            size_t g = ((size_t)(t * HH + gy) * WWD + gx) * CCH + ch0;
            uint2 a = *(const uint2*)(Vb + g);            // slot0  ch0..3
            uint2 b = *(const uint2*)(Vb + g + CCH);      // slot0+1 (gx+1)
            unsigned v0 = (a.x & 0xffffu) | (b.x << 16);
            unsigned v1 = (a.x >> 16)     | (b.x & 0xffff0000u);
            unsigned v2 = (a.y & 0xffffu) | (b.y << 16);
            unsigned v3 = (a.y >> 16)     | (b.y & 0xffff0000u);
            *(unsigned*)&Vt[(ch0 + 0) * 68 + slot0] = v0;
            *(unsigned*)&Vt[(ch0 + 1) * 68 + slot0] = v1;
            *(unsigned*)&Vt[(ch0 + 2) * 68 + slot0] = v2;
            *(unsigned*)&Vt[(ch0 + 3) * 68 + slot0] = v3;
        }
        __syncthreads();

        // fragment loads (shared across the 3 q-tiles)
        short4v kfr[4], vfr[4];
#pragma unroll
        for (int kt = 0; kt < 4; ++kt) {
            kfr[kt] = *(const short4v*)&Ks[(kt * 16 + l16) * 136 + h16 + quad * 4];
            vfr[kt] = *(const short4v*)&Vt[(h16 + l16) * 68 + kt * 16 + quad * 4];
        }

#pragma unroll
        for (int qt = 0; qt < 3; ++qt) {
            // scores (base-2 domain) with bias+mask injected through C
            float4v s[4];
#pragma unroll
            for (int kt = 0; kt < 4; ++kt) {
                float4v c;
#pragma unroll
                for (int r = 0; r < 4; ++r) {
                    int a = badr[kt * 4 + r];
                    c[r] = (a < 0) ? -1e30f : biasL[a + qt * 425];
                }
                s[kt] = MFMA16(kfr[kt], qfr[qt], c);
            }
            // online softmax (stats in q=l16 layout; cross-quad reduce = 2 shuffles)
            float mx = m[qt];
#pragma unroll
            for (int kt = 0; kt < 4; ++kt)
#pragma unroll
                for (int r = 0; r < 4; ++r) mx = fmaxf(mx, s[kt][r]);
            mx = fmaxf(mx, __shfl_xor(mx, 16));
            mx = fmaxf(mx, __shfl_xor(mx, 32));
            float corr = exp2f(m[qt] - mx);
            m[qt] = mx;
            l[qt] *= corr;
            float4v oc = oacc[qt] * corr;
            float lsum = 0.f;
            short4v pfr[4];
#pragma unroll
            for (int kt = 0; kt < 4; ++kt) {
                float p0 = exp2f(s[kt][0] - mx), p1 = exp2f(s[kt][1] - mx);
                float p2 = exp2f(s[kt][2] - mx), p3 = exp2f(s[kt][3] - mx);
                lsum += (p0 + p1) + (p2 + p3);
                union { short4v s4; unsigned short u[4]; } pk;
                pk.u[0] = f2bf(p0); pk.u[1] = f2bf(p1);
                pk.u[2] = f2bf(p2); pk.u[3] = f2bf(p3);
                pfr[kt] = pk.s4;
            }
            l[qt] += lsum;
            // PV: O^T accumulate; score D-frag == P B-frag, V^T A-frag from LDS
#pragma unroll
            for (int kt = 0; kt < 4; ++kt) oc = MFMA16(vfr[kt], pfr[kt], oc);
            oacc[qt] = oc;
        }
    }

    // ---- epilogue part 1: normalize O, stage bf16 rows to LDS (aliases Ks)
    __syncthreads();                      // all waves done with Ks/Vt/bias reads
#pragma unroll
    for (int qt = 0; qt < 3; ++qt) {
        float lt = l[qt];
        lt += __shfl_xor(lt, 16);
        lt += __shfl_xor(lt, 32);
        float inv = 1.f / lt;
        union { ushort4 u4; unsigned short u[4]; } ob;
#pragma unroll
        for (int r = 0; r < 4; ++r) ob.u[r] = f2bf(oacc[qt][r] * inv);
        *(ushort4*)&Os[(qt * 16 + l16) * 136 + h16 + quad * 4] = ob.u4;
    }
    __syncthreads();

    // ---- epilogue part 2: fused out-proj. wave w -> out-ch slab [w*16, w*16+16); D -> OF (LDS)
    float4v pacc[3];
#pragma unroll
    for (int nt = 0; nt < 3; ++nt) pacc[nt] = (float4v){0.f, 0.f, 0.f, 0.f};
#pragma unroll
    for (int ks = 0; ks < 4; ++ks) {
        short8 bfrag[3];
#pragma unroll
        for (int nt = 0; nt < 3; ++nt)
            bfrag[nt] = *(const short8*)&Os[(nt * 16 + l16) * 136 + ks * 32 + quad * 8];
        size_t wo = (size_t)(w * 16 + l16) * CCH + ks * 32 + quad * 8;
        short8 a1 = *(const short8*)(Wo1 + wo);
        short8 a2 = *(const short8*)(Wo2 + wo);
#pragma unroll
        for (int nt = 0; nt < 3; ++nt) {
            pacc[nt] = __builtin_amdgcn_mfma_f32_16x16x32_bf16(a1, bfrag[nt], pacc[nt], 0, 0, 0);
            pacc[nt] = __builtin_amdgcn_mfma_f32_16x16x32_bf16(a2, bfrag[nt], pacc[nt], 0, 0, 0);
        }
    }
#pragma unroll
    for (int nt = 0; nt < 3; ++nt) {      // OF[(qt*16 + query)][out-ch], query = l16 (D col), ch = quad*4+r (D row)
        float4v a = pacc[nt];
        float4 o; o.x = a[0]; o.y = a[1]; o.z = a[2]; o.w = a[3];
        *(float4*)&OF[(nt * 16 + l16) * 132 + w * 16 + quad * 4] = o;
    }
    __syncthreads();

    // ---- epilogue part 3: cooperative fully-coalesced copy OF -> out
    for (int i = tid; i < 1536; i += 512) {
        int cy = i / 384;                 // chunk
        int r  = i - cy * 384;            // float4 index within chunk (0..383)
        int row12 = r >> 5;               // 0..11 = cx*3 + nt
        int ch    = (r & 31) * 4;
        int cx = row12 / 3, nt = row12 - cx * 3;
        float4 v = *(const float4*)&OF[(nt * 16 + cy * 4 + cx) * 132 + ch];
        size_t g = ((size_t)((y0 + cy) * WWD + x0) * TT) * CCH + r * 4;
        *(float4*)(out + g) = v;
    }
}

extern "C" void kernel_launch(void* const* d_in, const int* in_sizes, int n_in,
                              void* d_out, int out_size, void* d_ws, size_t ws_size,
                              hipStream_t stream) {
    const float* x        = (const float*)d_in[0];
    const float* Wq       = (const float*)d_in[1];
    const float* Wk       = (const float*)d_in[2];
    const float* Wv       = (const float*)d_in[3];
    const float* Wo       = (const float*)d_in[4];
    const float* temp_emb = (const float*)d_in[5];
    const float* sp_emb   = (const float*)d_in[6];
    float* out = (float*)d_out;

    const size_t nb = (size_t)NROWS * CCH * 2;   // bytes per bf16 buffer
    unsigned short* Qb  = (unsigned short*)d_ws;
    unsigned short* Kb  = (unsigned short*)((char*)d_ws + nb);
    unsigned short* Vb  = (unsigned short*)((char*)d_ws + 2 * nb);
    unsigned short* Wt  = (unsigned short*)((char*)d_ws + 3 * nb);
    unsigned short* Wo1 = Wt + 384 * 128;
    unsigned short* Wo2 = Wo1 + 128 * 128;

    prep_kernel<<<64, 256, 0, stream>>>(Wq, Wk, Wv, Wo, Wt, Wo1, Wo2);
    qkv_kernel<<<NROWS / 64, 512, 0, stream>>>(x, Wt, temp_emb, sp_emb, Qb, Kb, Vb);
    attn_kernel<<<(HH / PX) * (WWD / PX), 512, 0, stream>>>(Qb, Kb, Vb, sp_emb, Wo1, Wo2, out);
}